// Round 4
// baseline (9608.182 us; speedup 1.0000x reference)
//
#include <hip/hip_runtime.h>
#include <hip/hip_cooperative_groups.h>
#include <math.h>

namespace cg = cooperative_groups;

#define N_   3072
#define D_   4
#define M_   512
#define NPAD 3200
#define NB   128
#define PW   32
#define NBLK (NPAD/NB)   // 25
#define MBLK (M_/NB)     // 4
#define JITTER_ 0.05f
#define CBORD 32768.0f
#define CH_T  512
#define CH_GRID 256

// ============================================================================
//                    Fused cooperative Cholesky chain
// ============================================================================
// Lookahead schedule per step k: phase1 = trsm(k) [all wgs]; phase2 =
// {wg<nmat: diag-syrk + potrf+inv(k+1)} || {others: trailing syrk(k)}.
// LDS: LT 64KB + SM 52KB (union: Wp+Tt / As+Bs / Pc) + pivd.

__device__ void potrf_duty(float* A, int lda, int b, int presub,
                           float* Tinv, float* logsum, int slot, int limit,
                           float* LT, float* SM, float* pivd) {
  const int tid = threadIdx.x;
  const int j0 = b * NB;
  for (int t = tid; t < NB*NB; t += CH_T) {
    int r = t & 127, c = t >> 7;
    LT[c*NB + r] = (c <= r) ? A[(size_t)(j0+r)*lda + (j0+c)] : 0.f;
  }
  if (presub) {
    float* Pc = SM;  // 128 x 33
    const int p0 = (b-1) * NB;
    for (int cs = 0; cs < NB; cs += 32) {
      __syncthreads();
      for (int t = tid; t < 128*8; t += CH_T) {
        int r = t >> 3, q = t & 7;
        float4 v = *(const float4*)&A[(size_t)(j0+r)*lda + p0 + cs + q*4];
        Pc[r*33 + q*4+0] = v.x; Pc[r*33 + q*4+1] = v.y;
        Pc[r*33 + q*4+2] = v.z; Pc[r*33 + q*4+3] = v.w;
      }
      __syncthreads();
      for (int t = tid; t < NB*NB; t += CH_T) {
        int r = t & 127, c = t >> 7;
        if (c <= r) {
          float s = 0.f;
          #pragma unroll
          for (int kk = 0; kk < 32; ++kk) s += Pc[r*33+kk]*Pc[c*33+kk];
          LT[c*NB + r] -= s;
        }
      }
    }
  }
  __syncthreads();
  // ---- factor (raw-pivot panels of 32, rank-32 trailing updates) ----
  #pragma unroll
  for (int p = 0; p < 4; ++p) {
    const int pc0 = p*PW, pc1 = pc0 + PW;
    for (int j = pc0; j < pc1; ++j) {
      float dd = fmaxf(LT[j*NB + j], 1e-30f);
      if (tid == 0) pivd[j] = dd;
      float rd = 1.0f / dd;
      int wn = pc1 - 1 - j;
      for (int t = tid; t < wn*NB; t += CH_T) {
        int c = j + 1 + (t >> 7);
        int i = t & 127;
        if (i >= c) LT[c*NB + i] -= LT[j*NB + i] * LT[j*NB + c] * rd;
      }
      __syncthreads();
    }
    for (int t = tid; t < PW*NB; t += CH_T) {
      int jc = pc0 + (t >> 7);
      int i  = t & 127;
      float dd = pivd[jc];
      if (i > jc)       LT[jc*NB + i] *= rsqrtf(dd);
      else if (i == jc) LT[jc*NB + i] = sqrtf(dd);
    }
    __syncthreads();
    if (pc1 < NB) {
      const int rem = NB - pc1;
      for (int t = tid; t < rem*rem; t += CH_T) {
        int cc = t / rem, rr = t - cc*rem;
        int c = pc1 + cc, i = pc1 + rr;
        if (i >= c) {
          float s = 0.f;
          #pragma unroll
          for (int jj = 0; jj < PW; ++jj)
            s += LT[(pc0+jj)*NB + i] * LT[(pc0+jj)*NB + c];
          LT[c*NB + i] -= s;
        }
      }
      __syncthreads();
    }
  }
  // ---- store L + log(diag) ----
  for (int t = tid; t < NB*NB; t += CH_T) {
    int r = t & 127, c = t >> 7;
    if (c <= r) A[(size_t)(j0+r)*lda + (j0+c)] = LT[c*NB + r];
  }
  {
    float lg = 0.f;
    if (tid < NB) {
      int g = j0 + tid;
      if (g < limit) lg = 0.5f * logf(pivd[tid]);
    }
    for (int o = 32; o; o >>= 1) lg += __shfl_down(lg, o);
    int wv = tid >> 6;
    if ((tid & 63) == 0 && wv < 2) logsum[slot*2 + wv] = lg;
  }
  // ---- blocked inverse ----
  float* Wp = SM;
  float* Tt = SM + 10240;
  for (int t = tid; t < 4*1024; t += CH_T) {
    int I = t >> 10, e = t & 1023;
    int r = e >> 5, c = e & 31;
    Wp[(I*(I+1)/2 + I)*1024 + e] = (r == c) ? 1.f : 0.f;
  }
  __syncthreads();
  {
    int wI = tid >> 7;
    int lane = tid & 127;
    float* Rb = &Wp[(wI*(wI+1)/2 + wI)*1024];
    for (int j = 0; j < 32; ++j) {
      float dinv = 1.0f / LT[(wI*32+j)*NB + (wI*32+j)];
      for (int t = lane; t < 1024; t += 128) {
        int i = t >> 5, c = t & 31;
        if (i > j && c <= j)
          Rb[i*32 + c] -= LT[(wI*32+j)*NB + (wI*32+i)] * Rb[j*32 + c] * dinv;
      }
      __syncthreads();
    }
    for (int t = lane; t < 1024; t += 128) {
      int i = t >> 5, c = t & 31;
      if (c <= i) Rb[i*32 + c] *= 1.0f / LT[(wI*32+i)*NB + (wI*32+i)];
    }
    __syncthreads();
  }
  #pragma unroll
  for (int dist = 1; dist < 4; ++dist) {
    const int nb = 4 - dist;
    for (int t = tid; t < nb*1024; t += CH_T) {
      int bb = t >> 10, e = t & 1023;
      int r = e >> 5, c = e & 31;
      int J = bb, I = bb + dist;
      float s = 0.f;
      for (int K = J; K < I; ++K) {
        const float* Wkj = &Wp[(K*(K+1)/2 + J)*1024];
        #pragma unroll
        for (int k = 0; k < 32; ++k)
          s += LT[(K*32+k)*NB + (I*32+r)] * Wkj[k*32 + c];
      }
      Tt[bb*1024 + e] = s;
    }
    __syncthreads();
    for (int t = tid; t < nb*1024; t += CH_T) {
      int bb = t >> 10, e = t & 1023;
      int r = e >> 5, c = e & 31;
      int J = bb, I = bb + dist;
      const float* Wii = &Wp[(I*(I+1)/2 + I)*1024];
      float s = 0.f;
      #pragma unroll
      for (int k = 0; k < 32; ++k)
        s += Wii[r*32 + k] * Tt[bb*1024 + k*32 + c];
      Wp[(I*(I+1)/2 + J)*1024 + e] = -s;
    }
    __syncthreads();
  }
  for (int t = tid; t < NB*32; t += CH_T) {
    int i = t >> 5, c4 = (t & 31) * 4;
    int I = i >> 5, J = c4 >> 5;
    float4 v;
    if (J <= I) {
      const float* Wij = &Wp[(I*(I+1)/2 + J)*1024 + (i & 31)*32 + (c4 & 31)];
      v = *(const float4*)Wij;
    } else v = make_float4(0.f, 0.f, 0.f, 0.f);
    *(float4*)&Tinv[i*NB + c4] = v;
  }
}

__device__ void trsm_tile(float* A, int lda, int bi, int bk, const float* Tinv,
                          float* As, float* Ts) {
  const int tid = threadIdx.x;
  const int tx = tid & 15, ty = tid >> 4;
  const int r0 = bi*NB, k0 = bk*NB;
  float acc[4][8];
  #pragma unroll
  for (int i = 0; i < 4; ++i)
    #pragma unroll
    for (int u = 0; u < 8; ++u) acc[i][u] = 0.f;
  for (int ks = 0; ks < NB; ks += 32) {
    __syncthreads();
    for (int t = tid; t < 128*8; t += CH_T) {
      int r = t >> 3, q = t & 7;
      float4 v = *(const float4*)&A[(size_t)(r0+r)*lda + k0 + ks + q*4];
      As[(q*4+0)*132+r]=v.x; As[(q*4+1)*132+r]=v.y;
      As[(q*4+2)*132+r]=v.z; As[(q*4+3)*132+r]=v.w;
      float4 w = *(const float4*)&Tinv[r*NB + ks + q*4];
      Ts[(q*4+0)*132+r]=w.x; Ts[(q*4+1)*132+r]=w.y;
      Ts[(q*4+2)*132+r]=w.z; Ts[(q*4+3)*132+r]=w.w;
    }
    __syncthreads();
    #pragma unroll
    for (int kk = 0; kk < 32; ++kk) {
      float a[4], bb[8];
      *(float4*)a      = *(const float4*)&As[kk*132 + ty*4];
      *(float4*)&bb[0] = *(const float4*)&Ts[kk*132 + tx*8];
      *(float4*)&bb[4] = *(const float4*)&Ts[kk*132 + tx*8 + 4];
      #pragma unroll
      for (int i = 0; i < 4; ++i)
        #pragma unroll
        for (int u = 0; u < 8; ++u) acc[i][u] += a[i]*bb[u];
    }
  }
  #pragma unroll
  for (int i = 0; i < 4; ++i) {
    size_t off = (size_t)(r0 + ty*4 + i)*lda + k0 + tx*8;
    *(float4*)&A[off]     = make_float4(acc[i][0],acc[i][1],acc[i][2],acc[i][3]);
    *(float4*)&A[off + 4] = make_float4(acc[i][4],acc[i][5],acc[i][6],acc[i][7]);
  }
}

__device__ void syrk_tile(float* A, int lda, int bi, int bj, int bk,
                          float* As, float* Bs) {
  const int tid = threadIdx.x;
  const int tx = tid & 15, ty = tid >> 4;
  const int r0 = bi*NB, c0 = bj*NB, k0 = bk*NB;
  float acc[4][8];
  #pragma unroll
  for (int i = 0; i < 4; ++i)
    #pragma unroll
    for (int u = 0; u < 8; ++u) acc[i][u] = 0.f;
  for (int ks = 0; ks < NB; ks += 32) {
    __syncthreads();
    for (int t = tid; t < 128*8; t += CH_T) {
      int r = t >> 3, q = t & 7;
      float4 v = *(const float4*)&A[(size_t)(r0+r)*lda + k0 + ks + q*4];
      As[(q*4+0)*132+r]=v.x; As[(q*4+1)*132+r]=v.y;
      As[(q*4+2)*132+r]=v.z; As[(q*4+3)*132+r]=v.w;
      float4 w = *(const float4*)&A[(size_t)(c0+r)*lda + k0 + ks + q*4];
      Bs[(q*4+0)*132+r]=w.x; Bs[(q*4+1)*132+r]=w.y;
      Bs[(q*4+2)*132+r]=w.z; Bs[(q*4+3)*132+r]=w.w;
    }
    __syncthreads();
    #pragma unroll
    for (int kk = 0; kk < 32; ++kk) {
      float a[4], bb[8];
      *(float4*)a      = *(const float4*)&As[kk*132 + ty*4];
      *(float4*)&bb[0] = *(const float4*)&Bs[kk*132 + tx*8];
      *(float4*)&bb[4] = *(const float4*)&Bs[kk*132 + tx*8 + 4];
      #pragma unroll
      for (int i = 0; i < 4; ++i)
        #pragma unroll
        for (int u = 0; u < 8; ++u) acc[i][u] += a[i]*bb[u];
    }
  }
  #pragma unroll
  for (int i = 0; i < 4; ++i) {
    size_t off = (size_t)(r0 + ty*4 + i)*lda + c0 + tx*8;
    float4 v0 = *(const float4*)&A[off];
    float4 v1 = *(const float4*)&A[off + 4];
    v0.x -= acc[i][0]; v0.y -= acc[i][1]; v0.z -= acc[i][2]; v0.w -= acc[i][3];
    v1.x -= acc[i][4]; v1.y -= acc[i][5]; v1.z -= acc[i][6]; v1.w -= acc[i][7];
    *(float4*)&A[off]     = v0;
    *(float4*)&A[off + 4] = v1;
  }
}

__global__ __launch_bounds__(CH_T, 1)
void k_chol_fused(float* Abase, size_t aStride, int lda, int nblk, int nmat,
                  float* TinvBase, size_t tStrideZ, size_t tStrideK,
                  float* logsum, int slotBase, int limit) {
  __shared__ __align__(16) float LT[NB*NB];
  __shared__ __align__(16) float SM[13312];
  __shared__ float pivd[NB];
  cg::grid_group grid = cg::this_grid();
  const int wg  = blockIdx.x;
  const int nwg = gridDim.x;

  if (wg < nmat) {
    potrf_duty(Abase + (size_t)wg*aStride, lda, 0, 0,
               TinvBase + (size_t)wg*tStrideZ, logsum, slotBase + wg*32, limit,
               LT, SM, pivd);
  }
  __threadfence();
  grid.sync();

  for (int k = 0; k <= nblk-2; ++k) {
    const int m = nblk - 1 - k;
    // phase 1: trsm(k) over nmat*m panel tiles
    for (int g = wg; g < nmat*m; g += nwg) {
      int z = g % nmat, ii = g / nmat;
      trsm_tile(Abase + (size_t)z*aStride, lda, k+1+ii, k,
                TinvBase + (size_t)z*tStrideZ + (size_t)k*tStrideK,
                SM, SM + 4224);
    }
    __threadfence();
    grid.sync();
    // phase 2: potrf(k+1) || trailing syrk(k)
    if (wg < nmat) {
      potrf_duty(Abase + (size_t)wg*aStride, lda, k+1, 1,
                 TinvBase + (size_t)wg*tStrideZ + (size_t)(k+1)*tStrideK,
                 logsum, slotBase + wg*32 + (k+1), limit, LT, SM, pivd);
    } else {
      int Ttri = m*(m+1)/2;
      int nwork = nmat*(Ttri - 1);
      int w = wg - nmat, nworkers = nwg - nmat;
      for (int g = w; g < nwork; g += nworkers) {
        int z = g / (Ttri - 1);
        int idx = 1 + g % (Ttri - 1);
        int iP = (int)((sqrtf(8.f*(float)idx + 1.f) - 1.f)*0.5f);
        while ((iP+1)*(iP+2)/2 <= idx) ++iP;
        while (iP*(iP+1)/2 > idx) --iP;
        int jP = idx - iP*(iP+1)/2;
        syrk_tile(Abase + (size_t)z*aStride, lda, k+1+iP, k+1+jP, k,
                  SM, SM + 4224);
      }
    }
    __threadfence();
    grid.sync();
  }
}

// ============================================================================
//            Fallback launch-chain kernels (R3 path, kept verbatim)
// ============================================================================
__global__ __launch_bounds__(256)
void k_potrf_inv(float* Abase, size_t aStride, int lda, int kblk,
                 float* TinvBase, size_t tStride, int doInv,
                 float* logsum, int slotBase, int limit) {
  __shared__ float LT[NB*NB];
  __shared__ float Wp[10*PW*PW];
  __shared__ float Tt[3*PW*PW];
  __shared__ float pivd[NB];
  const int tid = threadIdx.x;
  float* A = Abase + (size_t)blockIdx.z * aStride;
  const int j0 = kblk * NB;
  for (int t = tid; t < NB*NB; t += 256) {
    int r = t & 127, c = t >> 7;
    LT[c*NB + r] = (c <= r) ? A[(size_t)(j0 + r)*lda + (j0 + c)] : 0.f;
  }
  __syncthreads();
  #pragma unroll
  for (int p = 0; p < 4; ++p) {
    const int pc0 = p*PW, pc1 = pc0 + PW;
    for (int j = pc0; j < pc1; ++j) {
      float d = fmaxf(LT[j*NB + j], 1e-30f);
      if (tid == 0) pivd[j] = d;
      float rd = 1.0f / d;
      int w = pc1 - 1 - j;
      for (int t = tid; t < w*NB; t += 256) {
        int c = j + 1 + (t >> 7);
        int i = t & 127;
        if (i >= c) LT[c*NB + i] -= LT[j*NB + i] * LT[j*NB + c] * rd;
      }
      __syncthreads();
    }
    for (int t = tid; t < PW*NB; t += 256) {
      int jc = pc0 + (t >> 7);
      int i  = t & 127;
      float dd = pivd[jc];
      if (i > jc)       LT[jc*NB + i] *= rsqrtf(dd);
      else if (i == jc) LT[jc*NB + i] = sqrtf(dd);
    }
    __syncthreads();
    if (pc1 < NB) {
      const int rem = NB - pc1;
      for (int t = tid; t < rem*rem; t += 256) {
        int cc = t / rem, rr = t - cc*rem;
        int c = pc1 + cc, i = pc1 + rr;
        if (i >= c) {
          float s = 0.f;
          #pragma unroll
          for (int jj = 0; jj < PW; ++jj)
            s += LT[(pc0+jj)*NB + i] * LT[(pc0+jj)*NB + c];
          LT[c*NB + i] -= s;
        }
      }
      __syncthreads();
    }
  }
  for (int t = tid; t < NB*NB; t += 256) {
    int r = t & 127, c = t >> 7;
    if (c <= r) A[(size_t)(j0 + r)*lda + (j0 + c)] = LT[c*NB + r];
  }
  {
    float lg = 0.f;
    if (tid < NB) {
      int g = j0 + tid;
      if (g < limit) lg = 0.5f * logf(pivd[tid]);
    }
    for (int o = 32; o; o >>= 1) lg += __shfl_down(lg, o);
    int wv = tid >> 6;
    if ((tid & 63) == 0 && wv < 2)
      logsum[(slotBase + blockIdx.z*32 + kblk)*2 + wv] = lg;
  }
  if (!doInv) return;
  for (int t = tid; t < 4*1024; t += 256) {
    int I = t >> 10, e = t & 1023;
    int r = e >> 5, c = e & 31;
    Wp[(I*(I+1)/2 + I)*1024 + e] = (r == c) ? 1.f : 0.f;
  }
  __syncthreads();
  {
    int wI = tid >> 6;
    int lane = tid & 63;
    float* Rb = &Wp[(wI*(wI+1)/2 + wI)*1024];
    for (int j = 0; j < 32; ++j) {
      float dinv = 1.0f / LT[(wI*32+j)*NB + (wI*32+j)];
      for (int t = lane; t < 1024; t += 64) {
        int i = t >> 5, c = t & 31;
        if (i > j && c <= j)
          Rb[i*32 + c] -= LT[(wI*32+j)*NB + (wI*32+i)] * Rb[j*32 + c] * dinv;
      }
      __syncthreads();
    }
    for (int t = lane; t < 1024; t += 64) {
      int i = t >> 5, c = t & 31;
      if (c <= i) Rb[t] *= 1.0f / LT[(wI*32+i)*NB + (wI*32+i)];
    }
    __syncthreads();
  }
  #pragma unroll
  for (int dist = 1; dist < 4; ++dist) {
    const int nb = 4 - dist;
    for (int t = tid; t < nb*1024; t += 256) {
      int b = t >> 10, e = t & 1023;
      int r = e >> 5, c = e & 31;
      int J = b, I = b + dist;
      float s = 0.f;
      for (int K = J; K < I; ++K) {
        const float* Wkj = &Wp[(K*(K+1)/2 + J)*1024];
        #pragma unroll
        for (int k = 0; k < 32; ++k)
          s += LT[(K*32+k)*NB + (I*32+r)] * Wkj[k*32 + c];
      }
      Tt[b*1024 + e] = s;
    }
    __syncthreads();
    for (int t = tid; t < nb*1024; t += 256) {
      int b = t >> 10, e = t & 1023;
      int r = e >> 5, c = e & 31;
      int J = b, I = b + dist;
      const float* Wii = &Wp[(I*(I+1)/2 + I)*1024];
      float s = 0.f;
      #pragma unroll
      for (int k = 0; k < 32; ++k)
        s += Wii[r*32 + k] * Tt[b*1024 + k*32 + c];
      Wp[(I*(I+1)/2 + J)*1024 + e] = -s;
    }
    __syncthreads();
  }
  {
    float* Tinv = TinvBase + (size_t)blockIdx.z * tStride;
    for (int t = tid; t < NB*32; t += 256) {
      int i = t >> 5, c4 = (t & 31) * 4;
      int I = i >> 5, J = c4 >> 5;
      float4 v;
      if (J <= I) {
        const float* Wij = &Wp[(I*(I+1)/2 + J)*1024 + (i & 31)*32 + (c4 & 31)];
        v = *(const float4*)Wij;
      } else v = make_float4(0.f, 0.f, 0.f, 0.f);
      *(float4*)&Tinv[i*NB + c4] = v;
    }
  }
}

__global__ __launch_bounds__(256)
void k_trsm(float* Abase, size_t aStride, int lda, int kblk,
            const float* TinvBase, size_t tStride) {
  __shared__ float As[32*68];
  __shared__ float Ts[32*132];
  const int tid = threadIdx.x;
  float* A = Abase + (size_t)blockIdx.z * aStride;
  const float* Tinv = TinvBase + (size_t)blockIdx.z * tStride;
  const int k0 = kblk * NB;
  const int row0 = k0 + NB + blockIdx.x * 64;
  const int tx = tid & 15, ty = tid >> 4;
  float acc[4][8];
  #pragma unroll
  for (int i = 0; i < 4; ++i)
    #pragma unroll
    for (int u = 0; u < 8; ++u) acc[i][u] = 0.f;
  for (int ks = 0; ks < NB; ks += 32) {
    for (int t = tid; t < 64*8; t += 256) {
      int r = t >> 3, q = t & 7;
      float4 v = *(const float4*)&A[(size_t)(row0 + r)*lda + k0 + ks + q*4];
      As[(q*4+0)*68 + r] = v.x; As[(q*4+1)*68 + r] = v.y;
      As[(q*4+2)*68 + r] = v.z; As[(q*4+3)*68 + r] = v.w;
    }
    for (int t = tid; t < 128*8; t += 256) {
      int c = t >> 3, q = t & 7;
      float4 v = *(const float4*)&Tinv[c*NB + ks + q*4];
      Ts[(q*4+0)*132 + c] = v.x; Ts[(q*4+1)*132 + c] = v.y;
      Ts[(q*4+2)*132 + c] = v.z; Ts[(q*4+3)*132 + c] = v.w;
    }
    __syncthreads();
    #pragma unroll
    for (int kk = 0; kk < 32; ++kk) {
      float a[4], b[8];
      *(float4*)a      = *(const float4*)&As[kk*68 + ty*4];
      *(float4*)&b[0]  = *(const float4*)&Ts[kk*132 + tx*8];
      *(float4*)&b[4]  = *(const float4*)&Ts[kk*132 + tx*8 + 4];
      #pragma unroll
      for (int i = 0; i < 4; ++i)
        #pragma unroll
        for (int u = 0; u < 8; ++u) acc[i][u] += a[i]*b[u];
    }
    __syncthreads();
  }
  #pragma unroll
  for (int i = 0; i < 4; ++i) {
    int r = row0 + ty*4 + i;
    *(float4*)&A[(size_t)r*lda + k0 + tx*8]     = make_float4(acc[i][0],acc[i][1],acc[i][2],acc[i][3]);
    *(float4*)&A[(size_t)r*lda + k0 + tx*8 + 4] = make_float4(acc[i][4],acc[i][5],acc[i][6],acc[i][7]);
  }
}

__global__ __launch_bounds__(256)
void k_syrk(float* Abase, size_t aStride, int lda, int kblk) {
  if (blockIdx.y > blockIdx.x) return;
  __shared__ float As[32*68];
  __shared__ float Bs[32*68];
  const int tid = threadIdx.x;
  float* A = Abase + (size_t)blockIdx.z * aStride;
  const int k0 = kblk * NB;
  const int row0 = k0 + NB + blockIdx.x * 64;
  const int col0 = k0 + NB + blockIdx.y * 64;
  const int tx = tid & 15, ty = tid >> 4;
  float acc[4][4];
  #pragma unroll
  for (int i=0;i<4;++i) { acc[i][0]=0.f;acc[i][1]=0.f;acc[i][2]=0.f;acc[i][3]=0.f; }
  for (int ks = 0; ks < NB; ks += 32) {
    for (int t = tid; t < 64*8; t += 256) {
      int r = t >> 3, q = t & 7;
      float4 v = *(const float4*)&A[(size_t)(row0 + r)*lda + k0 + ks + q*4];
      As[(q*4+0)*68 + r] = v.x; As[(q*4+1)*68 + r] = v.y;
      As[(q*4+2)*68 + r] = v.z; As[(q*4+3)*68 + r] = v.w;
      float4 w = *(const float4*)&A[(size_t)(col0 + r)*lda + k0 + ks + q*4];
      Bs[(q*4+0)*68 + r] = w.x; Bs[(q*4+1)*68 + r] = w.y;
      Bs[(q*4+2)*68 + r] = w.z; Bs[(q*4+3)*68 + r] = w.w;
    }
    __syncthreads();
    #pragma unroll
    for (int kk = 0; kk < 32; ++kk) {
      float a[4], b[4];
      *(float4*)a = *(const float4*)&As[kk*68 + ty*4];
      *(float4*)b = *(const float4*)&Bs[kk*68 + tx*4];
      #pragma unroll
      for (int i=0;i<4;++i)
        #pragma unroll
        for (int u=0;u<4;++u) acc[i][u] += a[i]*b[u];
    }
    __syncthreads();
  }
  #pragma unroll
  for (int i=0;i<4;++i) {
    size_t off = (size_t)(row0 + ty*4 + i)*lda + col0 + tx*4;
    float4 v = *(const float4*)&A[off];
    v.x -= acc[i][0]; v.y -= acc[i][1]; v.z -= acc[i][2]; v.w -= acc[i][3];
    *(float4*)&A[off] = v;
  }
}

// ============================================================================
//                          common small kernels
// ============================================================================
__global__ __launch_bounds__(256)
void k_build_kb(const float* Xbar, const float* lsp, const float* stdp, const float* noisep,
                float* KbBase, size_t kbStride, int dimBase) {
  int z = blockIdx.z, d = dimBase + z;
  float* Kb = KbBase + (size_t)z*kbStride;
  int idx = blockIdx.x*256 + threadIdx.x;
  if (idx >= M_*M_) return;
  int i = idx >> 9, j = idx & 511;
  float ls = lsp[d], sd = stdp[d], nz = noisep[d];
  float df = Xbar[i*D_ + d] - Xbar[j*D_ + d];
  float v = sd*sd*expf(-0.5f*df*df/(ls*ls));
  if (i == j) v += nz*nz;
  Kb[idx] = v;
}

__global__ __launch_bounds__(256)
void k_build_kstar(const float* X, const float* Xbar, const float* lsp, const float* stdp,
                   float* KSBase, size_t ksStride, int dimBase) {
  int z = blockIdx.z, d = dimBase + z;
  float* KS = KSBase + (size_t)z*ksStride;
  int idx = blockIdx.x*256 + threadIdx.x;
  if (idx >= N_*M_) return;
  int i = idx >> 9, j = idx & 511;
  float ls = lsp[d], sd = stdp[d];
  float df = X[i*D_ + d] - Xbar[j*D_ + d];
  KS[idx] = sd*sd*expf(-0.5f*df*df/(ls*ls));
}

__global__ __launch_bounds__(256)
void k_csolve(float* CBase, size_t cStride, const float* KbBase, size_t kbStride,
              const float* TinvKbBase, size_t tkbStride, int J) {
  __shared__ float sm[12672];
  const int tid = threadIdx.x;
  float* C = CBase + (size_t)blockIdx.z*cStride;
  const float* L = KbBase + (size_t)blockIdx.z*kbStride;
  const float* Tinv = TinvKbBase + (size_t)blockIdx.z*tkbStride + (size_t)J*NB*NB;
  const int row0 = blockIdx.x*64;
  const int tx = tid & 15, ty = tid >> 4;
  float* As = sm; float* Ls = sm + 2176;
  float* Xs = sm; float* Ts = sm + 8448;
  float acc[4][8];
  #pragma unroll
  for (int i=0;i<4;++i) {
    const float* p = &C[(size_t)(row0+ty*4+i)*M_ + J*NB + tx*8];
    float4 v0 = *(const float4*)p, v1 = *(const float4*)(p+4);
    acc[i][0]=v0.x; acc[i][1]=v0.y; acc[i][2]=v0.z; acc[i][3]=v0.w;
    acc[i][4]=v1.x; acc[i][5]=v1.y; acc[i][6]=v1.z; acc[i][7]=v1.w;
  }
  for (int P = 0; P < J; ++P) {
    for (int ks = 0; ks < NB; ks += 32) {
      __syncthreads();
      for (int t = tid; t < 64*8; t += 256) {
        int r = t >> 3, q = t & 7;
        float4 v = *(const float4*)&C[(size_t)(row0+r)*M_ + P*NB + ks + q*4];
        As[(q*4+0)*68+r]=v.x; As[(q*4+1)*68+r]=v.y; As[(q*4+2)*68+r]=v.z; As[(q*4+3)*68+r]=v.w;
      }
      for (int t = tid; t < 128*8; t += 256) {
        int c = t >> 3, q = t & 7;
        float4 v = *(const float4*)&L[(size_t)(J*NB+c)*M_ + P*NB + ks + q*4];
        Ls[(q*4+0)*132+c]=v.x; Ls[(q*4+1)*132+c]=v.y; Ls[(q*4+2)*132+c]=v.z; Ls[(q*4+3)*132+c]=v.w;
      }
      __syncthreads();
      #pragma unroll
      for (int kk = 0; kk < 32; ++kk) {
        float a[4], b[8];
        *(float4*)a     = *(const float4*)&As[kk*68 + ty*4];
        *(float4*)&b[0] = *(const float4*)&Ls[kk*132 + tx*8];
        *(float4*)&b[4] = *(const float4*)&Ls[kk*132 + tx*8 + 4];
        #pragma unroll
        for (int i=0;i<4;++i)
          #pragma unroll
          for (int u=0;u<8;++u) acc[i][u] -= a[i]*b[u];
      }
    }
  }
  __syncthreads();
  #pragma unroll
  for (int i=0;i<4;++i)
    #pragma unroll
    for (int u=0;u<8;++u) Xs[(ty*4+i)*132 + tx*8+u] = acc[i][u];
  #pragma unroll
  for (int i=0;i<4;++i)
    #pragma unroll
    for (int u=0;u<8;++u) acc[i][u] = 0.f;
  for (int ms = 0; ms < NB; ms += 32) {
    for (int t = tid; t < 128*8; t += 256) {
      int c = t >> 3, q = t & 7;
      float4 v = *(const float4*)&Tinv[c*NB + ms + q*4];
      Ts[(q*4+0)*132+c]=v.x; Ts[(q*4+1)*132+c]=v.y; Ts[(q*4+2)*132+c]=v.z; Ts[(q*4+3)*132+c]=v.w;
    }
    __syncthreads();
    #pragma unroll
    for (int mm = 0; mm < 32; ++mm) {
      float a[4], b[8];
      a[0]=Xs[(ty*4+0)*132+ms+mm]; a[1]=Xs[(ty*4+1)*132+ms+mm];
      a[2]=Xs[(ty*4+2)*132+ms+mm]; a[3]=Xs[(ty*4+3)*132+ms+mm];
      *(float4*)&b[0] = *(const float4*)&Ts[mm*132 + tx*8];
      *(float4*)&b[4] = *(const float4*)&Ts[mm*132 + tx*8 + 4];
      #pragma unroll
      for (int i=0;i<4;++i)
        #pragma unroll
        for (int u=0;u<8;++u) acc[i][u] += a[i]*b[u];
    }
    __syncthreads();
  }
  #pragma unroll
  for (int i=0;i<4;++i) {
    float* p = &C[(size_t)(row0+ty*4+i)*M_ + J*NB + tx*8];
    *(float4*)p     = make_float4(acc[i][0],acc[i][1],acc[i][2],acc[i][3]);
    *(float4*)(p+4) = make_float4(acc[i][4],acc[i][5],acc[i][6],acc[i][7]);
  }
}

__global__ __launch_bounds__(256)
void k_fwdsub(const float* KbBase, size_t kbStride,
              const float* TkbBase, size_t tkbStride,
              const float* lls, float* wBase, size_t wStride, int dimBase) {
  __shared__ float w[M_];
  __shared__ float tv[NB];
  __shared__ float red[256];
  int z = blockIdx.z, d = dimBase + z;
  const float* L = KbBase + (size_t)z*kbStride;
  const float* Tk = TkbBase + (size_t)z*tkbStride;
  float* wout = wBase + (size_t)z*wStride;
  const int tid = threadIdx.x;
  for (int i = tid; i < M_; i += 256) w[i] = logf(fabsf(lls[i*D_ + d]));
  __syncthreads();
  const int r = tid >> 1, h = tid & 1;
  for (int J = 0; J < 4; ++J) {
    float s = 0.f;
    int half = (J*NB) >> 1;
    for (int k = h*half; k < (h+1)*half; k += 4) {
      float4 lv = *(const float4*)&L[(size_t)(J*NB + r)*M_ + k];
      s += lv.x*w[k] + lv.y*w[k+1] + lv.z*w[k+2] + lv.w*w[k+3];
    }
    red[tid] = s;
    __syncthreads();
    if (h == 0) tv[r] = w[J*NB + r] - red[2*r] - red[2*r+1];
    __syncthreads();
    const float* Ti = Tk + (size_t)J*NB*NB;
    s = 0.f;
    for (int k = h*64; k < h*64 + 64; k += 4) {
      float4 tw = *(const float4*)&Ti[r*NB + k];
      s += tw.x*tv[k] + tw.y*tv[k+1] + tw.z*tv[k+2] + tw.w*tv[k+3];
    }
    red[tid] = s;
    __syncthreads();
    if (h == 0) w[J*NB + r] = red[2*r] + red[2*r+1];
    __syncthreads();
  }
  for (int i = tid; i < M_; i += 256) wout[i] = w[i];
}

__global__ __launch_bounds__(256)
void k_gemv_l(const float* CBase, size_t cStride, const float* wBase, size_t wStride,
              float* lvec, int dimBase) {
  int z = blockIdx.z, d = dimBase + z;
  const float* C = CBase + (size_t)z*cStride;
  const float* w = wBase + (size_t)z*wStride;
  __shared__ float ws[M_];
  for (int i = threadIdx.x; i < M_; i += 256) ws[i] = w[i];
  __syncthreads();
  int wid = threadIdx.x >> 6, lane = threadIdx.x & 63;
  int row = blockIdx.x*4 + wid;
  if (row >= N_) return;
  float s = 0.f;
  const float* cr = &C[(size_t)row*M_];
  for (int k = lane; k < M_; k += 64) s += cr[k]*ws[k];
  for (int o = 32; o; o >>= 1) s += __shfl_down(s, o);
  if (lane == 0) lvec[row*D_ + d] = expf(s);
}

__global__ __launch_bounds__(256)
void k_kpost(const float* X, const float* lsp, const float* stdp,
             const float* CBase, size_t cStride,
             float* Abase, size_t aStride, int dimBase) {
  if (blockIdx.y > blockIdx.x) return;
  __shared__ float As[32*68];
  __shared__ float Bs[32*68];
  int z = blockIdx.z, d = dimBase + z;
  const float* C = CBase + (size_t)z*cStride;
  float* A = Abase + (size_t)z*aStride;
  const int row0 = blockIdx.x*64, col0 = blockIdx.y*64;
  const int tid = threadIdx.x, tx = tid & 15, ty = tid >> 4;
  float acc[4][4];
  #pragma unroll
  for (int i=0;i<4;++i) { acc[i][0]=0.f;acc[i][1]=0.f;acc[i][2]=0.f;acc[i][3]=0.f; }
  if (row0 < N_) {
    for (int ks = 0; ks < M_; ks += 32) {
      for (int t = tid; t < 64*8; t += 256) {
        int r = t >> 3, q = t & 7;
        float4 v = *(const float4*)&C[(size_t)(row0+r)*M_ + ks + q*4];
        As[(q*4+0)*68+r]=v.x; As[(q*4+1)*68+r]=v.y; As[(q*4+2)*68+r]=v.z; As[(q*4+3)*68+r]=v.w;
        float4 w2 = *(const float4*)&C[(size_t)(col0+r)*M_ + ks + q*4];
        Bs[(q*4+0)*68+r]=w2.x; Bs[(q*4+1)*68+r]=w2.y; Bs[(q*4+2)*68+r]=w2.z; Bs[(q*4+3)*68+r]=w2.w;
      }
      __syncthreads();
      #pragma unroll
      for (int kk=0; kk<32; ++kk) {
        float a[4], b[4];
        *(float4*)a = *(const float4*)&As[kk*68 + ty*4];
        *(float4*)b = *(const float4*)&Bs[kk*68 + tx*4];
        #pragma unroll
        for (int i=0;i<4;++i)
          #pragma unroll
          for (int u=0;u<4;++u) acc[i][u] += a[i]*b[u];
      }
      __syncthreads();
    }
  }
  float ls = lsp[d], sd = stdp[d];
  float inv2 = -0.5f/(ls*ls), s2 = sd*sd;
  #pragma unroll
  for (int i=0;i<4;++i) {
    int gi = row0 + ty*4 + i;
    float xi = (gi < N_) ? X[gi*D_ + d] : 0.f;
    #pragma unroll
    for (int u=0;u<4;++u) {
      int gj = col0 + tx*4 + u;
      float v;
      if (gi < N_ && gj < N_) {
        float df = xi - X[gj*D_ + d];
        v = s2*expf(inv2*df*df) - acc[i][u];
        if (gi == gj) v += JITTER_;
      } else {
        v = (gi == gj) ? 1.f : 0.f;
      }
      A[(size_t)gi*NPAD + gj] = v;
    }
  }
}

__global__ __launch_bounds__(256)
void k_kfinal(const float* X, const float* lvec, const float* y,
              const float* gstd, const float* gnoise, float* A) {
  int idx = blockIdx.x*256 + threadIdx.x;
  if (idx >= NPAD*NPAD) return;
  int gi = idx / NPAD, gj = idx - (idx/NPAD)*NPAD;
  float v;
  if (gi < N_ && gj < N_) {
    float gv = gstd[0]*gstd[0];
    float prod = 1.f, s = 0.f;
    #pragma unroll
    for (int d = 0; d < D_; ++d) {
      float l1 = lvec[gi*D_ + d], l2 = lvec[gj*D_ + d];
      float lsq = l1*l1 + l2*l2;
      prod *= 2.f*l1*l2/lsq;
      float df = X[gi*D_ + d] - X[gj*D_ + d];
      s += df*df/lsq;
    }
    v = gv * sqrtf(prod) * expf(-s);
    if (gi == gj) v += gnoise[0]*gnoise[0];
  } else if (gi == N_ && gj < N_) v = y[gj];
  else if (gj == N_ && gi < N_) v = y[gi];
  else if (gi == N_ && gj == N_) v = CBORD;
  else v = (gi == gj) ? 1.f : 0.f;
  A[idx] = v;
}

__global__ void k_finalize(const float* A, const float* logsum, float* out) {
  if (threadIdx.x != 0 || blockIdx.x != 0) return;
  float sumB = 0.f;
  for (int z = 0; z < 4; ++z)
    for (int k = 0; k < NBLK; ++k) {
      int slot = z*32 + k;
      sumB += logsum[slot*2] + logsum[slot*2+1];
    }
  float sumL = 0.f;
  for (int k = 0; k < NBLK; ++k) {
    int slot = 128 + k;
    sumL += logsum[slot*2] + logsum[slot*2+1];
  }
  float lb = A[(size_t)N_*NPAD + N_];
  float yKy = CBORD - lb*lb;
  const float LOG2PI = 1.8378770664093453f;
  float Aterm = 0.5f*(yKy + sumL + (float)N_*LOG2PI);
  float Bterm = sumB + 0.5f*(float)(M_*D_)*LOG2PI;
  out[0] = Aterm + Bterm;
}

// ============================================================================
extern "C" void kernel_launch(void* const* d_in, const int* in_sizes, int n_in,
                              void* d_out, int out_size, void* d_ws, size_t ws_size,
                              hipStream_t stream) {
  const float* X    = (const float*)d_in[0];
  const float* y    = (const float*)d_in[1];
  const float* Xbar = (const float*)d_in[2];
  const float* lgls = (const float*)d_in[3];
  const float* lgstd= (const float*)d_in[4];
  const float* lgnz = (const float*)d_in[5];
  const float* lls  = (const float*)d_in[6];
  const float* gstd = (const float*)d_in[7];
  const float* gnz  = (const float*)d_in[8];
  float* out = (float*)d_out;

  const size_t A_SZ   = (size_t)NPAD*NPAD;
  const size_t KS_SZ  = (size_t)N_*M_;
  const size_t KB_SZ  = (size_t)M_*M_;
  const size_t TKB_SZ = (size_t)4*NB*NB;
  const size_t TBG_SZ = (size_t)NB*NB;
  const size_t W_SZ   = (size_t)M_;
  const size_t LV_SZ  = (size_t)N_*D_;
  const size_t LOG_SZ = 1024;

  size_t need2 = (5*A_SZ + 4*(KS_SZ + KB_SZ + TKB_SZ + W_SZ) + 5*TBG_SZ
                  + LV_SZ + LOG_SZ + 1024);
  size_t per1  = A_SZ + KS_SZ + KB_SZ + TKB_SZ + TBG_SZ + W_SZ;
  size_t need1 = 4*per1 + LV_SZ + LOG_SZ + 256;

  int coop = 0;
  {
    int dev = 0;
    hipGetDevice(&dev);
    hipDeviceGetAttribute(&coop, hipDeviceAttributeCooperativeLaunch, dev);
  }

  if (coop && ws_size >= need2 * sizeof(float)) {
    // ---------- cooperative merged mode ----------
    float* p = (float*)d_ws;
    float* A    = p; p += 5*A_SZ;
    float* KS   = p; p += 4*KS_SZ;
    float* Kb   = p; p += 4*KB_SZ;
    float* Tkb  = p; p += 4*TKB_SZ;
    float* Tbig = p; p += 5*TBG_SZ;
    float* wv   = p; p += 4*W_SZ;
    float* lv   = p; p += LV_SZ;
    float* lgs  = p; p += LOG_SZ;

    k_build_kb<<<dim3((M_*M_+255)/256,1,4),256,0,stream>>>(Xbar,lgls,lgstd,lgnz,Kb,KB_SZ,0);
    {
      float* Aa = Kb; size_t aS = KB_SZ; int lda_ = M_; int nblk_ = MBLK; int nmat_ = 4;
      float* Tb = Tkb; size_t tz = TKB_SZ; size_t tk = (size_t)NB*NB;
      float* lg_ = lgs; int sb = 192; int lim = 0;
      void* args[] = {&Aa,&aS,&lda_,&nblk_,&nmat_,&Tb,&tz,&tk,&lg_,&sb,&lim};
      hipLaunchCooperativeKernel((const void*)k_chol_fused, dim3(CH_GRID), dim3(CH_T),
                                 args, 0, stream);
    }
    k_fwdsub<<<dim3(1,1,4),256,0,stream>>>(Kb,KB_SZ,Tkb,TKB_SZ,lls,wv,W_SZ,0);
    k_build_kstar<<<dim3((N_*M_+255)/256,1,4),256,0,stream>>>(X,Xbar,lgls,lgstd,KS,KS_SZ,0);
    for (int J = 0; J < MBLK; ++J)
      k_csolve<<<dim3(N_/64,1,4),256,0,stream>>>(KS,KS_SZ,Kb,KB_SZ,Tkb,TKB_SZ,J);
    k_gemv_l<<<dim3(N_/4,1,4),256,0,stream>>>(KS,KS_SZ,wv,W_SZ,lv,0);
    k_kpost<<<dim3(NPAD/64,NPAD/64,4),256,0,stream>>>(X,lgls,lgstd,KS,KS_SZ,A,A_SZ,0);
    k_kfinal<<<dim3((NPAD*NPAD+255)/256,1,1),256,0,stream>>>(X,lv,y,gstd,gnz,A+4*A_SZ);
    {
      float* Aa = A; size_t aS = A_SZ; int lda_ = NPAD; int nblk_ = NBLK; int nmat_ = 5;
      float* Tb = Tbig; size_t tz = TBG_SZ; size_t tk = 0;
      float* lg_ = lgs; int sb = 0; int lim = N_;
      void* args[] = {&Aa,&aS,&lda_,&nblk_,&nmat_,&Tb,&tz,&tk,&lg_,&sb,&lim};
      hipLaunchCooperativeKernel((const void*)k_chol_fused, dim3(CH_GRID), dim3(CH_T),
                                 args, 0, stream);
    }
    k_finalize<<<1,64,0,stream>>>(A+4*A_SZ,lgs,out);
    return;
  }

  if (ws_size >= need2 * sizeof(float)) {
    // ---------- merged mode, launch-chain (R3) ----------
    float* p = (float*)d_ws;
    float* A    = p; p += 5*A_SZ;
    float* KS   = p; p += 4*KS_SZ;
    float* Kb   = p; p += 4*KB_SZ;
    float* Tkb  = p; p += 4*TKB_SZ;
    float* Tbig = p; p += 5*TBG_SZ;
    float* wv   = p; p += 4*W_SZ;
    float* lv   = p; p += LV_SZ;
    float* lgs  = p; p += LOG_SZ;

    k_build_kb<<<dim3((M_*M_+255)/256,1,4),256,0,stream>>>(Xbar,lgls,lgstd,lgnz,Kb,KB_SZ,0);
    for (int k = 0; k < MBLK; ++k) {
      k_potrf_inv<<<dim3(1,1,4),256,0,stream>>>(Kb,KB_SZ,M_,k,Tkb+(size_t)k*NB*NB,TKB_SZ,1,lgs,192,0);
      if (k < MBLK-1) {
        int nt = (MBLK-1-k)*2;
        k_trsm<<<dim3(nt,1,4),256,0,stream>>>(Kb,KB_SZ,M_,k,Tkb+(size_t)k*NB*NB,TKB_SZ);
        k_syrk<<<dim3(nt,nt,4),256,0,stream>>>(Kb,KB_SZ,M_,k);
      }
    }
    k_fwdsub<<<dim3(1,1,4),256,0,stream>>>(Kb,KB_SZ,Tkb,TKB_SZ,lls,wv,W_SZ,0);
    k_build_kstar<<<dim3((N_*M_+255)/256,1,4),256,0,stream>>>(X,Xbar,lgls,lgstd,KS,KS_SZ,0);
    for (int J = 0; J < MBLK; ++J)
      k_csolve<<<dim3(N_/64,1,4),256,0,stream>>>(KS,KS_SZ,Kb,KB_SZ,Tkb,TKB_SZ,J);
    k_gemv_l<<<dim3(N_/4,1,4),256,0,stream>>>(KS,KS_SZ,wv,W_SZ,lv,0);
    k_kpost<<<dim3(NPAD/64,NPAD/64,4),256,0,stream>>>(X,lgls,lgstd,KS,KS_SZ,A,A_SZ,0);
    k_kfinal<<<dim3((NPAD*NPAD+255)/256,1,1),256,0,stream>>>(X,lv,y,gstd,gnz,A+4*A_SZ);
    for (int k = 0; k < NBLK; ++k) {
      k_potrf_inv<<<dim3(1,1,5),256,0,stream>>>(A,A_SZ,NPAD,k,Tbig,TBG_SZ,(k<NBLK-1)?1:0,lgs,0,N_);
      if (k < NBLK-1) {
        int nt = (NBLK-1-k)*2;
        k_trsm<<<dim3(nt,1,5),256,0,stream>>>(A,A_SZ,NPAD,k,Tbig,TBG_SZ);
        k_syrk<<<dim3(nt,nt,5),256,0,stream>>>(A,A_SZ,NPAD,k);
      }
    }
    k_finalize<<<1,64,0,stream>>>(A+4*A_SZ,lgs,out);
    return;
  }

  // ---------- small-ws fallback (R2 path) ----------
  bool batched = ws_size >= need1 * sizeof(float);
  int nz = batched ? 4 : 1;
  float* p = (float*)d_ws;
  float* A    = p; p += (size_t)nz*A_SZ;
  float* KS   = p; p += (size_t)nz*KS_SZ;
  float* Kb   = p; p += (size_t)nz*KB_SZ;
  float* Tkb  = p; p += (size_t)nz*TKB_SZ;
  float* Tbig = p; p += (size_t)nz*TBG_SZ;
  float* wv   = p; p += (size_t)nz*W_SZ;
  float* lv   = p; p += LV_SZ;
  float* lgs  = p; p += LOG_SZ;

  int npass = batched ? 1 : 4;
  for (int pass = 0; pass < npass; ++pass) {
    int dimBase  = batched ? 0 : pass;
    int slotBase = batched ? 0 : pass*32;
    k_build_kb<<<dim3((M_*M_+255)/256,1,nz),256,0,stream>>>(Xbar,lgls,lgstd,lgnz,Kb,KB_SZ,dimBase);
    for (int k = 0; k < MBLK; ++k) {
      k_potrf_inv<<<dim3(1,1,nz),256,0,stream>>>(Kb,KB_SZ,M_,k,Tkb+(size_t)k*NB*NB,TKB_SZ,1,lgs,192+slotBase,0);
      if (k < MBLK-1) {
        int nt = (MBLK-1-k)*2;
        k_trsm<<<dim3(nt,1,nz),256,0,stream>>>(Kb,KB_SZ,M_,k,Tkb+(size_t)k*NB*NB,TKB_SZ);
        k_syrk<<<dim3(nt,nt,nz),256,0,stream>>>(Kb,KB_SZ,M_,k);
      }
    }
    k_fwdsub<<<dim3(1,1,nz),256,0,stream>>>(Kb,KB_SZ,Tkb,TKB_SZ,lls,wv,W_SZ,dimBase);
    k_build_kstar<<<dim3((N_*M_+255)/256,1,nz),256,0,stream>>>(X,Xbar,lgls,lgstd,KS,KS_SZ,dimBase);
    for (int J = 0; J < MBLK; ++J)
      k_csolve<<<dim3(N_/64,1,nz),256,0,stream>>>(KS,KS_SZ,Kb,KB_SZ,Tkb,TKB_SZ,J);
    k_gemv_l<<<dim3(N_/4,1,nz),256,0,stream>>>(KS,KS_SZ,wv,W_SZ,lv,dimBase);
    k_kpost<<<dim3(NPAD/64,NPAD/64,nz),256,0,stream>>>(X,lgls,lgstd,KS,KS_SZ,A,A_SZ,dimBase);
    for (int k = 0; k < NBLK; ++k) {
      k_potrf_inv<<<dim3(1,1,nz),256,0,stream>>>(A,A_SZ,NPAD,k,Tbig,TBG_SZ,(k<NBLK-1)?1:0,lgs,slotBase,N_);
      if (k < NBLK-1) {
        int nt = (NBLK-1-k)*2;
        k_trsm<<<dim3(nt,1,nz),256,0,stream>>>(A,A_SZ,NPAD,k,Tbig,TBG_SZ);
        k_syrk<<<dim3(nt,nt,nz),256,0,stream>>>(A,A_SZ,NPAD,k);
      }
    }
  }
  k_kfinal<<<dim3((NPAD*NPAD+255)/256,1,1),256,0,stream>>>(X,lv,y,gstd,gnz,A);
  for (int k = 0; k < NBLK; ++k) {
    k_potrf_inv<<<dim3(1,1,1),256,0,stream>>>(A,A_SZ,NPAD,k,Tbig,TBG_SZ,(k<NBLK-1)?1:0,lgs,128,N_);
    if (k < NBLK-1) {
      int nt = (NBLK-1-k)*2;
      k_trsm<<<dim3(nt,1,1),256,0,stream>>>(A,A_SZ,NPAD,k,Tbig,TBG_SZ);
      k_syrk<<<dim3(nt,nt,1),256,0,stream>>>(A,A_SZ,NPAD,k);
    }
  }
  k_finalize<<<1,64,0,stream>>>(A,lgs,out);
}

// Round 5
// 7999.964 us; speedup vs baseline: 1.2010x; 1.2010x over previous
//
#include <hip/hip_runtime.h>
#include <math.h>

#define N_   3072
#define D_   4
#define M_   512
#define NPAD 3200
#define NB   128
#define PW   32
#define NBLK (NPAD/NB)   // 25
#define MBLK (M_/NB)     // 4
#define JITTER_ 0.05f
#define CBORD 32768.0f
#define LTS  132         // padded LDS stride for LT (col-major LT[c*LTS+r])

// ============================================================================
// 64x64 syrk tile: A[gr0..,gc0..] -= P_r * P_c^T, P from cols [k0,k0+128).
// 256-thread engine (R3-proven 68-stride layout, 2-way-free banks).
// ============================================================================
__device__ void syrk64(float* A, int lda, int gr0, int gc0, int k0, int valid,
                       float* As, float* Bs, int lt) {
  const int tx = lt & 15, ty = lt >> 4;
  float acc[4][4];
  #pragma unroll
  for (int i=0;i<4;++i){acc[i][0]=0.f;acc[i][1]=0.f;acc[i][2]=0.f;acc[i][3]=0.f;}
  for (int ks = 0; ks < NB; ks += 32) {
    __syncthreads();
    if (valid) {
      for (int t = lt; t < 64*8; t += 256) {
        int rr = t >> 3, qq = t & 7;
        float4 v = *(const float4*)&A[(size_t)(gr0+rr)*lda + k0 + ks + qq*4];
        As[(qq*4+0)*68+rr]=v.x; As[(qq*4+1)*68+rr]=v.y;
        As[(qq*4+2)*68+rr]=v.z; As[(qq*4+3)*68+rr]=v.w;
        float4 w = *(const float4*)&A[(size_t)(gc0+rr)*lda + k0 + ks + qq*4];
        Bs[(qq*4+0)*68+rr]=w.x; Bs[(qq*4+1)*68+rr]=w.y;
        Bs[(qq*4+2)*68+rr]=w.z; Bs[(qq*4+3)*68+rr]=w.w;
      }
    }
    __syncthreads();
    if (valid) {
      #pragma unroll
      for (int kk = 0; kk < 32; ++kk) {
        float a[4], b[4];
        *(float4*)a = *(const float4*)&As[kk*68 + ty*4];
        *(float4*)b = *(const float4*)&Bs[kk*68 + tx*4];
        #pragma unroll
        for (int i=0;i<4;++i)
          #pragma unroll
          for (int u=0;u<4;++u) acc[i][u] += a[i]*b[u];
      }
    }
  }
  if (valid) {
    #pragma unroll
    for (int i=0;i<4;++i) {
      size_t off = (size_t)(gr0 + ty*4 + i)*lda + gc0 + tx*4;
      float4 v = *(const float4*)&A[off];
      v.x -= acc[i][0]; v.y -= acc[i][1]; v.z -= acc[i][2]; v.w -= acc[i][3];
      *(float4*)&A[off] = v;
    }
  }
}

// presub variant: accumulate into LDS LT (lower-masked). P rows j0.., cols p0..
__device__ void presub64(const float* A, int lda, int j0, int p0, int sr, int sc,
                         int valid, float* As, float* Bs, float* LT_, int lt) {
  const int tx = lt & 15, ty = lt >> 4;
  float acc[4][4];
  #pragma unroll
  for (int i=0;i<4;++i){acc[i][0]=0.f;acc[i][1]=0.f;acc[i][2]=0.f;acc[i][3]=0.f;}
  for (int ks = 0; ks < NB; ks += 32) {
    __syncthreads();
    if (valid) {
      for (int t = lt; t < 64*8; t += 256) {
        int rr = t >> 3, qq = t & 7;
        float4 v = *(const float4*)&A[(size_t)(j0+sr*64+rr)*lda + p0 + ks + qq*4];
        As[(qq*4+0)*68+rr]=v.x; As[(qq*4+1)*68+rr]=v.y;
        As[(qq*4+2)*68+rr]=v.z; As[(qq*4+3)*68+rr]=v.w;
        float4 w = *(const float4*)&A[(size_t)(j0+sc*64+rr)*lda + p0 + ks + qq*4];
        Bs[(qq*4+0)*68+rr]=w.x; Bs[(qq*4+1)*68+rr]=w.y;
        Bs[(qq*4+2)*68+rr]=w.z; Bs[(qq*4+3)*68+rr]=w.w;
      }
    }
    __syncthreads();
    if (valid) {
      #pragma unroll
      for (int kk = 0; kk < 32; ++kk) {
        float a[4], b[4];
        *(float4*)a = *(const float4*)&As[kk*68 + ty*4];
        *(float4*)b = *(const float4*)&Bs[kk*68 + tx*4];
        #pragma unroll
        for (int i=0;i<4;++i)
          #pragma unroll
          for (int u=0;u<4;++u) acc[i][u] += a[i]*b[u];
      }
    }
  }
  if (valid) {
    #pragma unroll
    for (int i=0;i<4;++i)
      #pragma unroll
      for (int u=0;u<4;++u) {
        int rr = sr*64 + ty*4 + i, cc = sc*64 + tx*4 + u;
        if (cc <= rr) LT_[cc*LTS + rr] -= acc[i][u];
      }
  }
}

// ============================================================================
// potrf(+optional presub of panel p0=j0-NB)(+optional inverse). 512 threads.
// Coalesced IO, padded-132 col-major LT, register-tiled trailing updates.
// ============================================================================
__device__ void potrf_duty(float* A, int lda, int b, int presub, int doInv,
                           float* Tinv, float* logsum, int slot, int limit,
                           float* LT_, float* SM_, float* pivd_) {
  const int tid = threadIdx.x;
  const int j0 = b * NB;
  // coalesced load (row-major global -> col-major padded LDS)
  for (int t = tid; t < NB*NB; t += 512) {
    int r = t >> 7, c = t & 127;
    float v = 0.f;
    if (c <= r) v = A[(size_t)(j0+r)*lda + (j0+c)];
    LT_[c*LTS + r] = v;
  }
  if (presub) {
    int half = tid >> 8, lt = tid & 255;
    float* As = SM_ + half*4352; float* Bs = As + 2176;
    const int p0 = j0 - NB;
    presub64(A, lda, j0, p0, half, 0, 1, As, Bs, LT_, lt);          // (0,0),(1,0)
    presub64(A, lda, j0, p0, 1, 1, half==0 ? 1 : 0, As, Bs, LT_, lt); // (1,1),dummy
  }
  __syncthreads();
  // ---- factor: 4 panels of 32, raw pivots (1 barrier/step) ----
  #pragma unroll
  for (int p = 0; p < 4; ++p) {
    const int pc0 = p*PW, pc1 = pc0 + PW;
    for (int j = pc0; j < pc1; ++j) {
      float dd = fmaxf(LT_[j*LTS + j], 1e-30f);
      if (tid == 0) pivd_[j] = dd;
      float rd = 1.0f / dd;
      int wn = pc1 - 1 - j;
      for (int t = tid; t < wn*NB; t += 512) {
        int c = j + 1 + (t >> 7);
        int i = t & 127;
        if (i >= c) LT_[c*LTS + i] -= LT_[j*LTS + i] * LT_[j*LTS + c] * rd;
      }
      __syncthreads();
    }
    for (int t = tid; t < PW*NB; t += 512) {
      int jc = pc0 + (t >> 7);
      int i  = t & 127;
      float dd = pivd_[jc];
      if (i > jc)       LT_[jc*LTS + i] *= rsqrtf(dd);
      else if (i == jc) LT_[jc*LTS + i] = sqrtf(dd);
    }
    __syncthreads();
    // rank-32 trailing update, register-tiled 4x4
    if (pc1 < NB) {
      const int rem = NB - pc1, g4 = rem >> 2;
      for (int t = tid; t < g4*g4; t += 512) {
        int tr = t / g4, tc = t - tr*g4;
        if (tc > tr) continue;
        int i0 = pc1 + tr*4, c0 = pc1 + tc*4;
        float acc2[4][4];
        #pragma unroll
        for (int i=0;i<4;++i){acc2[i][0]=0.f;acc2[i][1]=0.f;acc2[i][2]=0.f;acc2[i][3]=0.f;}
        #pragma unroll
        for (int jj = 0; jj < PW; ++jj) {
          float av[4], bv[4];
          *(float4*)av = *(const float4*)&LT_[(pc0+jj)*LTS + i0];
          *(float4*)bv = *(const float4*)&LT_[(pc0+jj)*LTS + c0];
          #pragma unroll
          for (int i=0;i<4;++i)
            #pragma unroll
            for (int u=0;u<4;++u) acc2[i][u] += av[i]*bv[u];
        }
        #pragma unroll
        for (int i=0;i<4;++i)
          #pragma unroll
          for (int u=0;u<4;++u) {
            int rr = i0+i, cc = c0+u;
            if (cc <= rr) LT_[cc*LTS + rr] -= acc2[i][u];
          }
      }
      __syncthreads();
    }
  }
  // store L (coalesced)
  for (int t = tid; t < NB*NB; t += 512) {
    int r = t >> 7, c = t & 127;
    if (c <= r) A[(size_t)(j0+r)*lda + (j0+c)] = LT_[c*LTS + r];
  }
  // log(diag) partial sums
  {
    float lg = 0.f;
    if (tid < NB) {
      int g = j0 + tid;
      if (g < limit) lg = 0.5f * logf(pivd_[tid]);
    }
    for (int o = 32; o; o >>= 1) lg += __shfl_down(lg, o);
    int wv = tid >> 6;
    if ((tid & 63) == 0 && wv < 2) logsum[slot*2 + wv] = lg;
  }
  if (!doInv) return;
  // ---- blocked inverse (Wp packed lower blocks of W = inv(L)) ----
  float* Wp = SM_;
  float* Tt = SM_ + 10240;
  for (int t = tid; t < 4*1024; t += 512) {
    int I = t >> 10, e = t & 1023;
    int r = e >> 5, c = e & 31;
    Wp[(I*(I+1)/2 + I)*1024 + e] = (r == c) ? 1.f : 0.f;
  }
  __syncthreads();
  {
    int wI = tid >> 7;
    int lane = tid & 127;
    float* Rb = &Wp[(wI*(wI+1)/2 + wI)*1024];
    for (int j = 0; j < 32; ++j) {
      float dinv = 1.0f / LT_[(wI*32+j)*LTS + (wI*32+j)];
      for (int t = lane; t < 1024; t += 128) {
        int i = t >> 5, c = t & 31;
        if (i > j && c <= j)
          Rb[i*32 + c] -= LT_[(wI*32+j)*LTS + (wI*32+i)] * Rb[j*32 + c] * dinv;
      }
      __syncthreads();
    }
    for (int t = lane; t < 1024; t += 128) {
      int i = t >> 5, c = t & 31;
      if (c <= i) Rb[i*32 + c] *= 1.0f / LT_[(wI*32+i)*LTS + (wI*32+i)];
    }
    __syncthreads();
  }
  #pragma unroll
  for (int dist = 1; dist < 4; ++dist) {
    const int nb = 4 - dist;
    for (int t = tid; t < nb*1024; t += 512) {
      int bb = t >> 10, e = t & 1023;
      int r = e >> 5, c = e & 31;
      int J = bb, I = bb + dist;
      float s = 0.f;
      for (int K = J; K < I; ++K) {
        const float* Wkj = &Wp[(K*(K+1)/2 + J)*1024];
        #pragma unroll
        for (int k = 0; k < 32; ++k)
          s += LT_[(K*32+k)*LTS + (I*32+r)] * Wkj[k*32 + c];
      }
      Tt[bb*1024 + e] = s;
    }
    __syncthreads();
    for (int t = tid; t < nb*1024; t += 512) {
      int bb = t >> 10, e = t & 1023;
      int r = e >> 5, c = e & 31;
      int J = bb, I = bb + dist;
      const float* Wii = &Wp[(I*(I+1)/2 + I)*1024];
      float s = 0.f;
      #pragma unroll
      for (int k = 0; k < 32; ++k)
        s += Wii[r*32 + k] * Tt[bb*1024 + k*32 + c];
      Wp[(I*(I+1)/2 + J)*1024 + e] = -s;
    }
    __syncthreads();
  }
  for (int t = tid; t < NB*32; t += 512) {
    int i = t >> 5, c4 = (t & 31) * 4;
    int I = i >> 5, J = c4 >> 5;
    float4 v;
    if (J <= I) {
      const float* Wij = &Wp[(I*(I+1)/2 + J)*1024 + (i & 31)*32 + (c4 & 31)];
      v = *(const float4*)Wij;
    } else v = make_float4(0.f, 0.f, 0.f, 0.f);
    *(float4*)&Tinv[i*NB + c4] = v;
  }
}

// ============================================================================
// Combined step: block 0 = potrf(+presub,+inv) of block bpot;
// blocks >=1 = trailing syrk(k) 64-tiles (minus the (bpot,bpot) diag block).
// Stream order replaces grid.sync -> lookahead overlap on one stream.
// ============================================================================
__global__ __launch_bounds__(512, 1)
void k_step(float* Abase, size_t aStride, int lda, int bpot, int presub, int doInv,
            float* TinvBase, size_t tStrideZ, size_t tStrideK,
            float* logsum, int slotBase, int limit,
            int R0, int q, int k0) {
  __shared__ __align__(16) float LT[128*LTS];
  __shared__ __align__(16) float SM[13312];
  __shared__ float pivd[NB];
  const int z = blockIdx.z;
  float* A = Abase + (size_t)z*aStride;

  if (blockIdx.x == 0) {
    potrf_duty(A, lda, bpot, presub, doInv,
               TinvBase + (size_t)z*tStrideZ + (size_t)bpot*tStrideK,
               logsum, slotBase + z*32 + bpot, limit, LT, SM, pivd);
    return;
  }
  const int tid = threadIdx.x;
  int half = tid >> 8, lt = tid & 255;
  int tileIdx = (blockIdx.x - 1)*2 + half;
  int ntiles = q*(q+1)/2 - 3;
  int valid = (tileIdx < ntiles) ? 1 : 0;
  int idxp = valid ? tileIdx + 3 : 3;  // first 3 lower-tri tiles = diag block (presub'd)
  int r = (int)((sqrtf(8.f*(float)idxp + 1.f) - 1.f)*0.5f);
  while ((r+1)*(r+2)/2 <= idxp) ++r;
  while (r*(r+1)/2 > idxp) --r;
  int c = idxp - r*(r+1)/2;
  syrk64(A, lda, (R0+r)*64, (R0+c)*64, k0, valid,
         SM + half*4352, SM + half*4352 + 2176, lt);
}

// ---------------- trsm: L21 = A21 * Tinv^T (R3-proven) ----------------
__global__ __launch_bounds__(256)
void k_trsm(float* Abase, size_t aStride, int lda, int kblk,
            const float* TinvBase, size_t tStride) {
  __shared__ float As[32*68];
  __shared__ float Ts[32*132];
  const int tid = threadIdx.x;
  float* A = Abase + (size_t)blockIdx.z * aStride;
  const float* Tinv = TinvBase + (size_t)blockIdx.z * tStride;
  const int k0 = kblk * NB;
  const int row0 = k0 + NB + blockIdx.x * 64;
  const int tx = tid & 15, ty = tid >> 4;
  float acc[4][8];
  #pragma unroll
  for (int i = 0; i < 4; ++i)
    #pragma unroll
    for (int u = 0; u < 8; ++u) acc[i][u] = 0.f;
  for (int ks = 0; ks < NB; ks += 32) {
    for (int t = tid; t < 64*8; t += 256) {
      int r = t >> 3, q = t & 7;
      float4 v = *(const float4*)&A[(size_t)(row0 + r)*lda + k0 + ks + q*4];
      As[(q*4+0)*68 + r] = v.x; As[(q*4+1)*68 + r] = v.y;
      As[(q*4+2)*68 + r] = v.z; As[(q*4+3)*68 + r] = v.w;
    }
    for (int t = tid; t < 128*8; t += 256) {
      int c = t >> 3, q = t & 7;
      float4 v = *(const float4*)&Tinv[c*NB + ks + q*4];
      Ts[(q*4+0)*132 + c] = v.x; Ts[(q*4+1)*132 + c] = v.y;
      Ts[(q*4+2)*132 + c] = v.z; Ts[(q*4+3)*132 + c] = v.w;
    }
    __syncthreads();
    #pragma unroll
    for (int kk = 0; kk < 32; ++kk) {
      float a[4], b[8];
      *(float4*)a      = *(const float4*)&As[kk*68 + ty*4];
      *(float4*)&b[0]  = *(const float4*)&Ts[kk*132 + tx*8];
      *(float4*)&b[4]  = *(const float4*)&Ts[kk*132 + tx*8 + 4];
      #pragma unroll
      for (int i = 0; i < 4; ++i)
        #pragma unroll
        for (int u = 0; u < 8; ++u) acc[i][u] += a[i]*b[u];
    }
    __syncthreads();
  }
  #pragma unroll
  for (int i = 0; i < 4; ++i) {
    int r = row0 + ty*4 + i;
    *(float4*)&A[(size_t)r*lda + k0 + tx*8]     = make_float4(acc[i][0],acc[i][1],acc[i][2],acc[i][3]);
    *(float4*)&A[(size_t)r*lda + k0 + tx*8 + 4] = make_float4(acc[i][4],acc[i][5],acc[i][6],acc[i][7]);
  }
}

// ---------------- builders / solves / epilogue (R3, unchanged) ----------------
__global__ __launch_bounds__(256)
void k_build_kb(const float* Xbar, const float* lsp, const float* stdp, const float* noisep,
                float* KbBase, size_t kbStride, int dimBase) {
  int z = blockIdx.z, d = dimBase + z;
  float* Kb = KbBase + (size_t)z*kbStride;
  int idx = blockIdx.x*256 + threadIdx.x;
  if (idx >= M_*M_) return;
  int i = idx >> 9, j = idx & 511;
  float ls = lsp[d], sd = stdp[d], nz = noisep[d];
  float df = Xbar[i*D_ + d] - Xbar[j*D_ + d];
  float v = sd*sd*expf(-0.5f*df*df/(ls*ls));
  if (i == j) v += nz*nz;
  Kb[idx] = v;
}

__global__ __launch_bounds__(256)
void k_build_kstar(const float* X, const float* Xbar, const float* lsp, const float* stdp,
                   float* KSBase, size_t ksStride, int dimBase) {
  int z = blockIdx.z, d = dimBase + z;
  float* KS = KSBase + (size_t)z*ksStride;
  int idx = blockIdx.x*256 + threadIdx.x;
  if (idx >= N_*M_) return;
  int i = idx >> 9, j = idx & 511;
  float ls = lsp[d], sd = stdp[d];
  float df = X[i*D_ + d] - Xbar[j*D_ + d];
  KS[idx] = sd*sd*expf(-0.5f*df*df/(ls*ls));
}

__global__ __launch_bounds__(256)
void k_csolve(float* CBase, size_t cStride, const float* KbBase, size_t kbStride,
              const float* TinvKbBase, size_t tkbStride, int J) {
  __shared__ float sm[12672];
  const int tid = threadIdx.x;
  float* C = CBase + (size_t)blockIdx.z*cStride;
  const float* L = KbBase + (size_t)blockIdx.z*kbStride;
  const float* Tinv = TinvKbBase + (size_t)blockIdx.z*tkbStride + (size_t)J*NB*NB;
  const int row0 = blockIdx.x*64;
  const int tx = tid & 15, ty = tid >> 4;
  float* As = sm; float* Ls = sm + 2176;
  float* Xs = sm; float* Ts = sm + 8448;
  float acc[4][8];
  #pragma unroll
  for (int i=0;i<4;++i) {
    const float* p = &C[(size_t)(row0+ty*4+i)*M_ + J*NB + tx*8];
    float4 v0 = *(const float4*)p, v1 = *(const float4*)(p+4);
    acc[i][0]=v0.x; acc[i][1]=v0.y; acc[i][2]=v0.z; acc[i][3]=v0.w;
    acc[i][4]=v1.x; acc[i][5]=v1.y; acc[i][6]=v1.z; acc[i][7]=v1.w;
  }
  for (int P = 0; P < J; ++P) {
    for (int ks = 0; ks < NB; ks += 32) {
      __syncthreads();
      for (int t = tid; t < 64*8; t += 256) {
        int r = t >> 3, q = t & 7;
        float4 v = *(const float4*)&C[(size_t)(row0+r)*M_ + P*NB + ks + q*4];
        As[(q*4+0)*68+r]=v.x; As[(q*4+1)*68+r]=v.y; As[(q*4+2)*68+r]=v.z; As[(q*4+3)*68+r]=v.w;
      }
      for (int t = tid; t < 128*8; t += 256) {
        int c = t >> 3, q = t & 7;
        float4 v = *(const float4*)&L[(size_t)(J*NB+c)*M_ + P*NB + ks + q*4];
        Ls[(q*4+0)*132+c]=v.x; Ls[(q*4+1)*132+c]=v.y; Ls[(q*4+2)*132+c]=v.z; Ls[(q*4+3)*132+c]=v.w;
      }
      __syncthreads();
      #pragma unroll
      for (int kk = 0; kk < 32; ++kk) {
        float a[4], b[8];
        *(float4*)a     = *(const float4*)&As[kk*68 + ty*4];
        *(float4*)&b[0] = *(const float4*)&Ls[kk*132 + tx*8];
        *(float4*)&b[4] = *(const float4*)&Ls[kk*132 + tx*8 + 4];
        #pragma unroll
        for (int i=0;i<4;++i)
          #pragma unroll
          for (int u=0;u<8;++u) acc[i][u] -= a[i]*b[u];
      }
    }
  }
  __syncthreads();
  #pragma unroll
  for (int i=0;i<4;++i)
    #pragma unroll
    for (int u=0;u<8;++u) Xs[(ty*4+i)*132 + tx*8+u] = acc[i][u];
  #pragma unroll
  for (int i=0;i<4;++i)
    #pragma unroll
    for (int u=0;u<8;++u) acc[i][u] = 0.f;
  for (int ms = 0; ms < NB; ms += 32) {
    for (int t = tid; t < 128*8; t += 256) {
      int c = t >> 3, q = t & 7;
      float4 v = *(const float4*)&Tinv[c*NB + ms + q*4];
      Ts[(q*4+0)*132+c]=v.x; Ts[(q*4+1)*132+c]=v.y; Ts[(q*4+2)*132+c]=v.z; Ts[(q*4+3)*132+c]=v.w;
    }
    __syncthreads();
    #pragma unroll
    for (int mm = 0; mm < 32; ++mm) {
      float a[4], b[8];
      a[0]=Xs[(ty*4+0)*132+ms+mm]; a[1]=Xs[(ty*4+1)*132+ms+mm];
      a[2]=Xs[(ty*4+2)*132+ms+mm]; a[3]=Xs[(ty*4+3)*132+ms+mm];
      *(float4*)&b[0] = *(const float4*)&Ts[mm*132 + tx*8];
      *(float4*)&b[4] = *(const float4*)&Ts[mm*132 + tx*8 + 4];
      #pragma unroll
      for (int i=0;i<4;++i)
        #pragma unroll
        for (int u=0;u<8;++u) acc[i][u] += a[i]*b[u];
    }
    __syncthreads();
  }
  #pragma unroll
  for (int i=0;i<4;++i) {
    float* p = &C[(size_t)(row0+ty*4+i)*M_ + J*NB + tx*8];
    *(float4*)p     = make_float4(acc[i][0],acc[i][1],acc[i][2],acc[i][3]);
    *(float4*)(p+4) = make_float4(acc[i][4],acc[i][5],acc[i][6],acc[i][7]);
  }
}

__global__ __launch_bounds__(256)
void k_fwdsub(const float* KbBase, size_t kbStride,
              const float* TkbBase, size_t tkbStride,
              const float* lls, float* wBase, size_t wStride, int dimBase) {
  __shared__ float w[M_];
  __shared__ float tv[NB];
  __shared__ float red[256];
  int z = blockIdx.z, d = dimBase + z;
  const float* L = KbBase + (size_t)z*kbStride;
  const float* Tk = TkbBase + (size_t)z*tkbStride;
  float* wout = wBase + (size_t)z*wStride;
  const int tid = threadIdx.x;
  for (int i = tid; i < M_; i += 256) w[i] = logf(fabsf(lls[i*D_ + d]));
  __syncthreads();
  const int r = tid >> 1, h = tid & 1;
  for (int J = 0; J < 4; ++J) {
    float s = 0.f;
    int half = (J*NB) >> 1;
    for (int k = h*half; k < (h+1)*half; k += 4) {
      float4 lv = *(const float4*)&L[(size_t)(J*NB + r)*M_ + k];
      s += lv.x*w[k] + lv.y*w[k+1] + lv.z*w[k+2] + lv.w*w[k+3];
    }
    red[tid] = s;
    __syncthreads();
    if (h == 0) tv[r] = w[J*NB + r] - red[2*r] - red[2*r+1];
    __syncthreads();
    const float* Ti = Tk + (size_t)J*NB*NB;
    s = 0.f;
    for (int k = h*64; k < h*64 + 64; k += 4) {
      float4 tw = *(const float4*)&Ti[r*NB + k];
      s += tw.x*tv[k] + tw.y*tv[k+1] + tw.z*tv[k+2] + tw.w*tv[k+3];
    }
    red[tid] = s;
    __syncthreads();
    if (h == 0) w[J*NB + r] = red[2*r] + red[2*r+1];
    __syncthreads();
  }
  for (int i = tid; i < M_; i += 256) wout[i] = w[i];
}

__global__ __launch_bounds__(256)
void k_gemv_l(const float* CBase, size_t cStride, const float* wBase, size_t wStride,
              float* lvec, int dimBase) {
  int z = blockIdx.z, d = dimBase + z;
  const float* C = CBase + (size_t)z*cStride;
  const float* w = wBase + (size_t)z*wStride;
  __shared__ float ws[M_];
  for (int i = threadIdx.x; i < M_; i += 256) ws[i] = w[i];
  __syncthreads();
  int wid = threadIdx.x >> 6, lane = threadIdx.x & 63;
  int row = blockIdx.x*4 + wid;
  if (row >= N_) return;
  float s = 0.f;
  const float* cr = &C[(size_t)row*M_];
  for (int k = lane; k < M_; k += 64) s += cr[k]*ws[k];
  for (int o = 32; o; o >>= 1) s += __shfl_down(s, o);
  if (lane == 0) lvec[row*D_ + d] = expf(s);
}

__global__ __launch_bounds__(256)
void k_kpost(const float* X, const float* lsp, const float* stdp,
             const float* CBase, size_t cStride,
             float* Abase, size_t aStride, int dimBase) {
  if (blockIdx.y > blockIdx.x) return;
  __shared__ float As[32*68];
  __shared__ float Bs[32*68];
  int z = blockIdx.z, d = dimBase + z;
  const float* C = CBase + (size_t)z*cStride;
  float* A = Abase + (size_t)z*aStride;
  const int row0 = blockIdx.x*64, col0 = blockIdx.y*64;
  const int tid = threadIdx.x, tx = tid & 15, ty = tid >> 4;
  float acc[4][4];
  #pragma unroll
  for (int i=0;i<4;++i) { acc[i][0]=0.f;acc[i][1]=0.f;acc[i][2]=0.f;acc[i][3]=0.f; }
  if (row0 < N_) {
    for (int ks = 0; ks < M_; ks += 32) {
      for (int t = tid; t < 64*8; t += 256) {
        int r = t >> 3, q = t & 7;
        float4 v = *(const float4*)&C[(size_t)(row0+r)*M_ + ks + q*4];
        As[(q*4+0)*68+r]=v.x; As[(q*4+1)*68+r]=v.y; As[(q*4+2)*68+r]=v.z; As[(q*4+3)*68+r]=v.w;
        float4 w2 = *(const float4*)&C[(size_t)(col0+r)*M_ + ks + q*4];
        Bs[(q*4+0)*68+r]=w2.x; Bs[(q*4+1)*68+r]=w2.y; Bs[(q*4+2)*68+r]=w2.z; Bs[(q*4+3)*68+r]=w2.w;
      }
      __syncthreads();
      #pragma unroll
      for (int kk=0; kk<32; ++kk) {
        float a[4], b[4];
        *(float4*)a = *(const float4*)&As[kk*68 + ty*4];
        *(float4*)b = *(const float4*)&Bs[kk*68 + tx*4];
        #pragma unroll
        for (int i=0;i<4;++i)
          #pragma unroll
          for (int u=0;u<4;++u) acc[i][u] += a[i]*b[u];
      }
      __syncthreads();
    }
  }
  float ls = lsp[d], sd = stdp[d];
  float inv2 = -0.5f/(ls*ls), s2 = sd*sd;
  #pragma unroll
  for (int i=0;i<4;++i) {
    int gi = row0 + ty*4 + i;
    float xi = (gi < N_) ? X[gi*D_ + d] : 0.f;
    #pragma unroll
    for (int u=0;u<4;++u) {
      int gj = col0 + tx*4 + u;
      float v;
      if (gi < N_ && gj < N_) {
        float df = xi - X[gj*D_ + d];
        v = s2*expf(inv2*df*df) - acc[i][u];
        if (gi == gj) v += JITTER_;
      } else {
        v = (gi == gj) ? 1.f : 0.f;
      }
      A[(size_t)gi*NPAD + gj] = v;
    }
  }
}

__global__ __launch_bounds__(256)
void k_kfinal(const float* X, const float* lvec, const float* y,
              const float* gstd, const float* gnoise, float* A) {
  int idx = blockIdx.x*256 + threadIdx.x;
  if (idx >= NPAD*NPAD) return;
  int gi = idx / NPAD, gj = idx - (idx/NPAD)*NPAD;
  float v;
  if (gi < N_ && gj < N_) {
    float gv = gstd[0]*gstd[0];
    float prod = 1.f, s = 0.f;
    #pragma unroll
    for (int d = 0; d < D_; ++d) {
      float l1 = lvec[gi*D_ + d], l2 = lvec[gj*D_ + d];
      float lsq = l1*l1 + l2*l2;
      prod *= 2.f*l1*l2/lsq;
      float df = X[gi*D_ + d] - X[gj*D_ + d];
      s += df*df/lsq;
    }
    v = gv * sqrtf(prod) * expf(-s);
    if (gi == gj) v += gnoise[0]*gnoise[0];
  } else if (gi == N_ && gj < N_) v = y[gj];
  else if (gj == N_ && gi < N_) v = y[gi];
  else if (gi == N_ && gj == N_) v = CBORD;
  else v = (gi == gj) ? 1.f : 0.f;
  A[idx] = v;
}

__global__ void k_finalize(const float* A, const float* logsum, float* out) {
  if (threadIdx.x != 0 || blockIdx.x != 0) return;
  float sumB = 0.f;
  for (int z = 0; z < 4; ++z)
    for (int k = 0; k < NBLK; ++k) {
      int slot = z*32 + k;
      sumB += logsum[slot*2] + logsum[slot*2+1];
    }
  float sumL = 0.f;
  for (int k = 0; k < NBLK; ++k) {
    int slot = 128 + k;
    sumL += logsum[slot*2] + logsum[slot*2+1];
  }
  float lb = A[(size_t)N_*NPAD + N_];
  float yKy = CBORD - lb*lb;
  const float LOG2PI = 1.8378770664093453f;
  float Aterm = 0.5f*(yKy + sumL + (float)N_*LOG2PI);
  float Bterm = sumB + 0.5f*(float)(M_*D_)*LOG2PI;
  out[0] = Aterm + Bterm;
}

// ============================================================================
// host helper: blocked Cholesky chain with lookahead (2 launches/step)
// ============================================================================
static void run_chain(float* A, size_t aS, int lda, int nblk,
                      float* Tinv, size_t tz, size_t tk, int invAll,
                      float* lgs, int slotBase, int limit, int nz,
                      hipStream_t stream) {
  int doInv0 = (invAll || nblk > 1) ? 1 : 0;
  k_step<<<dim3(1,1,nz),512,0,stream>>>(A,aS,lda, 0,0,doInv0, Tinv,tz,tk,
                                        lgs,slotBase,limit, 0,0,0);
  for (int k = 0; k < nblk-1; ++k) {
    int m = nblk-1-k;
    k_trsm<<<dim3(2*m,1,nz),256,0,stream>>>(A,aS,lda,k, Tinv + (size_t)k*tk, tz);
    int q2 = 2*m, ntiles = q2*(q2+1)/2 - 3;
    int nbx = 1 + (ntiles+1)/2;
    int doInv = (invAll || (k+1 < nblk-1)) ? 1 : 0;
    k_step<<<dim3(nbx,1,nz),512,0,stream>>>(A,aS,lda, k+1,1,doInv, Tinv,tz,tk,
                                            lgs,slotBase,limit, (k+1)*2, q2, k*NB);
  }
}

extern "C" void kernel_launch(void* const* d_in, const int* in_sizes, int n_in,
                              void* d_out, int out_size, void* d_ws, size_t ws_size,
                              hipStream_t stream) {
  const float* X    = (const float*)d_in[0];
  const float* y    = (const float*)d_in[1];
  const float* Xbar = (const float*)d_in[2];
  const float* lgls = (const float*)d_in[3];
  const float* lgstd= (const float*)d_in[4];
  const float* lgnz = (const float*)d_in[5];
  const float* lls  = (const float*)d_in[6];
  const float* gstd = (const float*)d_in[7];
  const float* gnz  = (const float*)d_in[8];
  float* out = (float*)d_out;

  const size_t A_SZ   = (size_t)NPAD*NPAD;
  const size_t KS_SZ  = (size_t)N_*M_;
  const size_t KB_SZ  = (size_t)M_*M_;
  const size_t TKB_SZ = (size_t)4*NB*NB;
  const size_t TBG_SZ = (size_t)NB*NB;
  const size_t W_SZ   = (size_t)M_;
  const size_t LV_SZ  = (size_t)N_*D_;
  const size_t LOG_SZ = 1024;

  size_t need2 = (5*A_SZ + 4*(KS_SZ + KB_SZ + TKB_SZ + W_SZ) + 5*TBG_SZ
                  + LV_SZ + LOG_SZ + 1024);
  size_t per1  = A_SZ + KS_SZ + KB_SZ + TKB_SZ + TBG_SZ + W_SZ;
  size_t need1 = 4*per1 + LV_SZ + LOG_SZ + 256;

  if (ws_size >= need2 * sizeof(float)) {
    // ---------- merged mode: one 25-step lookahead chain over 5 matrices ----
    float* p = (float*)d_ws;
    float* A    = p; p += 5*A_SZ;
    float* KS   = p; p += 4*KS_SZ;
    float* Kb   = p; p += 4*KB_SZ;
    float* Tkb  = p; p += 4*TKB_SZ;
    float* Tbig = p; p += 5*TBG_SZ;
    float* wv   = p; p += 4*W_SZ;
    float* lv   = p; p += LV_SZ;
    float* lgs  = p; p += LOG_SZ;

    k_build_kb<<<dim3((M_*M_+255)/256,1,4),256,0,stream>>>(Xbar,lgls,lgstd,lgnz,Kb,KB_SZ,0);
    run_chain(Kb, KB_SZ, M_, MBLK, Tkb, TKB_SZ, (size_t)NB*NB, 1, lgs, 192, 0, 4, stream);
    k_fwdsub<<<dim3(1,1,4),256,0,stream>>>(Kb,KB_SZ,Tkb,TKB_SZ,lls,wv,W_SZ,0);
    k_build_kstar<<<dim3((N_*M_+255)/256,1,4),256,0,stream>>>(X,Xbar,lgls,lgstd,KS,KS_SZ,0);
    for (int J = 0; J < MBLK; ++J)
      k_csolve<<<dim3(N_/64,1,4),256,0,stream>>>(KS,KS_SZ,Kb,KB_SZ,Tkb,TKB_SZ,J);
    k_gemv_l<<<dim3(N_/4,1,4),256,0,stream>>>(KS,KS_SZ,wv,W_SZ,lv,0);
    k_kpost<<<dim3(NPAD/64,NPAD/64,4),256,0,stream>>>(X,lgls,lgstd,KS,KS_SZ,A,A_SZ,0);
    k_kfinal<<<dim3((NPAD*NPAD+255)/256,1,1),256,0,stream>>>(X,lv,y,gstd,gnz,A+4*A_SZ);
    run_chain(A, A_SZ, NPAD, NBLK, Tbig, TBG_SZ, 0, 0, lgs, 0, N_, 5, stream);
    k_finalize<<<1,64,0,stream>>>(A+4*A_SZ,lgs,out);
    return;
  }

  // ---------- small-ws fallback: sequential passes ----------
  bool batched = ws_size >= need1 * sizeof(float);
  int nz = batched ? 4 : 1;
  float* p = (float*)d_ws;
  float* A    = p; p += (size_t)nz*A_SZ;
  float* KS   = p; p += (size_t)nz*KS_SZ;
  float* Kb   = p; p += (size_t)nz*KB_SZ;
  float* Tkb  = p; p += (size_t)nz*TKB_SZ;
  float* Tbig = p; p += (size_t)nz*TBG_SZ;
  float* wv   = p; p += (size_t)nz*W_SZ;
  float* lv   = p; p += LV_SZ;
  float* lgs  = p; p += LOG_SZ;

  int npass = batched ? 1 : 4;
  for (int pass = 0; pass < npass; ++pass) {
    int dimBase  = batched ? 0 : pass;
    int slotBase = batched ? 0 : pass*32;
    k_build_kb<<<dim3((M_*M_+255)/256,1,nz),256,0,stream>>>(Xbar,lgls,lgstd,lgnz,Kb,KB_SZ,dimBase);
    run_chain(Kb, KB_SZ, M_, MBLK, Tkb, TKB_SZ, (size_t)NB*NB, 1, lgs, 192+slotBase, 0, nz, stream);
    k_fwdsub<<<dim3(1,1,nz),256,0,stream>>>(Kb,KB_SZ,Tkb,TKB_SZ,lls,wv,W_SZ,dimBase);
    k_build_kstar<<<dim3((N_*M_+255)/256,1,nz),256,0,stream>>>(X,Xbar,lgls,lgstd,KS,KS_SZ,dimBase);
    for (int J = 0; J < MBLK; ++J)
      k_csolve<<<dim3(N_/64,1,nz),256,0,stream>>>(KS,KS_SZ,Kb,KB_SZ,Tkb,TKB_SZ,J);
    k_gemv_l<<<dim3(N_/4,1,nz),256,0,stream>>>(KS,KS_SZ,wv,W_SZ,lv,dimBase);
    k_kpost<<<dim3(NPAD/64,NPAD/64,nz),256,0,stream>>>(X,lgls,lgstd,KS,KS_SZ,A,A_SZ,dimBase);
    run_chain(A, A_SZ, NPAD, NBLK, Tbig, TBG_SZ, 0, 0, lgs, slotBase, N_, nz, stream);
  }
  k_kfinal<<<dim3((NPAD*NPAD+255)/256,1,1),256,0,stream>>>(X,lv,y,gstd,gnz,A);
  run_chain(A, A_SZ, NPAD, NBLK, Tbig, TBG_SZ, 0, 0, lgs, 128, N_, 1, stream);
  k_finalize<<<1,64,0,stream>>>(A,lgs,out);
}